// Round 11
// baseline (162.718 us; speedup 1.0000x reference)
//
#include <hip/hip_runtime.h>
#include <hip/hip_bf16.h>

typedef __attribute__((ext_vector_type(4))) float f32x4;
typedef __attribute__((ext_vector_type(16))) float f32x16;
typedef __attribute__((ext_vector_type(8))) short bf16x8;
typedef __attribute__((ext_vector_type(4))) unsigned int uint4v;
typedef __attribute__((ext_vector_type(2))) unsigned int uint2v;

#define MFMA16(a, b, c) __builtin_amdgcn_mfma_f32_16x16x32_bf16(a, b, c, 0, 0, 0)
#define MFMA32(a, b, c) __builtin_amdgcn_mfma_f32_32x32x16_bf16(a, b, c, 0, 0, 0)

__device__ __forceinline__ unsigned short f2bf(float f) {
  union { float f; unsigned u; } v; v.f = f;
  unsigned r = v.u + 0x7fffu + ((v.u >> 16) & 1u);
  return (unsigned short)(r >> 16);
}
// native converts (compiler pairs these into v_cvt_pk_bf16_f32 — m240)
__device__ __forceinline__ unsigned pack2(float a, float b) {
  union { __hip_bfloat162 h2; unsigned u; } cv;
  cv.h2 = __hip_bfloat162(__float2bfloat16(a), __float2bfloat16(b));
  return cv.u;
}

// cross-half exchange: returns (x = {a_lo, b_lo'}, y = {a_hi', b_hi}) per
// v_permlane32_swap_b32 semantics; fallback = 2 shfl + selects (round-10 proven)
__device__ __forceinline__ void swap32(unsigned a, unsigned b, int hi,
                                       unsigned& ox, unsigned& oy) {
#if __has_builtin(__builtin_amdgcn_permlane32_swap)
  uint2v r = __builtin_amdgcn_permlane32_swap(a, b, false, false);
  ox = r[0]; oy = r[1];
#else
  unsigned sb = __shfl_xor(b, 32);
  unsigned sa = __shfl_xor(a, 32);
  ox = hi ? sb : a;
  oy = hi ? b : sa;
#endif
}

// y = x @ W^T + b, optional scale, M=65536 rows, N=K=128.
template<bool IN_F32, int OUT_MODE>
__global__ __launch_bounds__(256)
void proj_kernel(const void* __restrict__ xin, const float* __restrict__ W,
                 const float* __restrict__ bias, void* __restrict__ yout,
                 float scale)
{
  __shared__ __align__(16) unsigned short Ws[128][136];
  __shared__ __align__(16) unsigned short Xs[64][136];
  const int t = threadIdx.x;
  const int wid = t >> 6;
  const int lane = t & 63;
  const int ln = lane & 15, g = lane >> 4;
  const long row0 = (long)blockIdx.x * 64;

  float bz[8];
#pragma unroll
  for (int tt = 0; tt < 8; ++tt) bz[tt] = bias[tt * 16 + ln];

#pragma unroll
  for (int i = 0; i < 16; ++i) {
    int idx = (i * 256 + t) * 4;
    int r = idx >> 7, c = idx & 127;
    const float4 w4 = *reinterpret_cast<const float4*>(W + idx);
    ushort4 wb;
    wb.x = f2bf(w4.x); wb.y = f2bf(w4.y); wb.z = f2bf(w4.z); wb.w = f2bf(w4.w);
    *reinterpret_cast<ushort4*>(&Ws[r][c]) = wb;
  }
  if (IN_F32) {
    const float* x = (const float*)xin;
#pragma unroll
    for (int i = 0; i < 8; ++i) {
      int idx = (i * 256 + t) * 4;
      int r = idx >> 7, c = idx & 127;
      const float4 x4 = *reinterpret_cast<const float4*>(x + row0 * 128 + idx);
      ushort4 xb;
      xb.x = f2bf(x4.x); xb.y = f2bf(x4.y); xb.z = f2bf(x4.z); xb.w = f2bf(x4.w);
      *reinterpret_cast<ushort4*>(&Xs[r][c]) = xb;
    }
  } else {
    const unsigned short* x = (const unsigned short*)xin;
#pragma unroll
    for (int i = 0; i < 4; ++i) {
      int idx = (i * 256 + t) * 8;
      int r = idx >> 7, c = idx & 127;
      *reinterpret_cast<uint4v*>(&Xs[r][c]) =
          *reinterpret_cast<const uint4v*>(x + row0 * 128 + idx);
    }
  }
  __syncthreads();

  f32x4 acc[8];
#pragma unroll
  for (int tt = 0; tt < 8; ++tt) acc[tt] = (f32x4){0.f, 0.f, 0.f, 0.f};

#pragma unroll
  for (int c = 0; c < 4; ++c) {
    bf16x8 af = *reinterpret_cast<const bf16x8*>(&Xs[wid * 16 + ln][c * 32 + g * 8]);
#pragma unroll
    for (int tt = 0; tt < 8; ++tt) {
      bf16x8 bfr = *reinterpret_cast<const bf16x8*>(&Ws[tt * 16 + ln][c * 32 + g * 8]);
      acc[tt] = MFMA16(af, bfr, acc[tt]);
    }
  }

#pragma unroll
  for (int tt = 0; tt < 8; ++tt) {
#pragma unroll
    for (int r = 0; r < 4; ++r) {
      long row = row0 + wid * 16 + g * 4 + r;
      int col = tt * 16 + ln;
      float val = (acc[tt][r] + bz[tt]) * scale;
      if (OUT_MODE == 2) {
        ((float*)yout)[row * 128 + col] = val;
      } else if (OUT_MODE == 0) {
        ((unsigned short*)yout)[row * 128 + col] = f2bf(val);
      } else {
        long bb = row >> 11, rr = row & 2047;
        ((unsigned short*)yout)[(bb * 128 + col) * 2048 + rr] = f2bf(val);
      }
    }
  }
}

// Flash attention, 32x32x16 MFMA, KVBLK=64 (32 iterations).
// 4 waves x 32 q-rows. Swapped QK^T; in-register P via permlane32_swap;
// native cvt_pk packing; defer-max THR=8 (log2 domain); T14 single-buffer
// staging with the round-8-proven barrier skeleton.
__global__ __launch_bounds__(256)
void attn_kernel(const unsigned short* __restrict__ Qg,
                 const unsigned short* __restrict__ Kg,
                 const unsigned short* __restrict__ Vtg,
                 unsigned short* __restrict__ Fg)
{
  __shared__ __align__(16) unsigned short Ks[64][136];
  __shared__ __align__(16) unsigned short Vs[128][72];

  const int t = threadIdx.x;          // 0..255
  const int lane = t & 63;
  const int q = lane & 31;
  const int hi = lane >> 5;
  const int wid = t >> 6;
  const int b = blockIdx.y;
  const int q0 = blockIdx.x * 128 + wid * 32;

  const unsigned short* Qb = Qg + (long)b * 2048 * 128;
  const unsigned short* Kb = Kg + (long)b * 2048 * 128;
  const unsigned short* Vb = Vtg + (long)b * 128 * 2048;

  // staging coords: K tile [64][128] -> 4 b128/thread; V^T tile [128][64] -> 4 b128/thread
  const int kr = t >> 4, kc = (t & 15) * 8;
  const int vc = t >> 3, vo = (t & 7) * 8;

  // Q fragments: qf[c][i] = Q[q0+q][c*16 + hi*8 + i]
  bf16x8 qf[8];
#pragma unroll
  for (int c = 0; c < 8; ++c)
    qf[c] = *reinterpret_cast<const bf16x8*>(
        Qb + (long)(q0 + q) * 128 + c * 16 + hi * 8);

  f32x16 o[4];
#pragma unroll
  for (int dc = 0; dc < 4; ++dc)
#pragma unroll
    for (int r = 0; r < 16; ++r) o[dc][r] = 0.f;
  float mrun = -1e30f;
  float lrun = 0.f;

  // prologue: issue tile 0's loads
  uint4v kreg[4], vreg[4];
#pragma unroll
  for (int i = 0; i < 4; ++i) {
    kreg[i] = *reinterpret_cast<const uint4v*>(Kb + (long)(kr + 16 * i) * 128 + kc);
    vreg[i] = *reinterpret_cast<const uint4v*>(Vb + (long)(vc + 32 * i) * 2048 + vo);
  }

  for (int kt = 0; kt < 32; ++kt) {
    __syncthreads();   // readers of previous tile done
#pragma unroll
    for (int i = 0; i < 4; ++i) {
      *reinterpret_cast<uint4v*>(&Ks[kr + 16 * i][kc]) = kreg[i];
      *reinterpret_cast<uint4v*>(&Vs[vc + 32 * i][vo]) = vreg[i];
    }
    __syncthreads();   // tile kt visible

    if (kt < 31) {     // T14: issue next tile's loads, consumed next iteration
      const int nv0 = (kt + 1) * 64;
#pragma unroll
      for (int i = 0; i < 4; ++i) {
        kreg[i] = *reinterpret_cast<const uint4v*>(Kb + (long)(nv0 + kr + 16 * i) * 128 + kc);
        vreg[i] = *reinterpret_cast<const uint4v*>(Vb + (long)(vc + 32 * i) * 2048 + nv0 + vo);
      }
    }

    // QK^T: st0 = S^T rows kv 0..31, st1 = kv 32..63 (reg r -> kv (r&3)+8*(r>>2)+4*hi [+32])
    f32x16 st0, st1;
#pragma unroll
    for (int r = 0; r < 16; ++r) { st0[r] = 0.f; st1[r] = 0.f; }
#pragma unroll
    for (int c = 0; c < 8; ++c) {
      bf16x8 kf0 = *reinterpret_cast<const bf16x8*>(&Ks[q][c * 16 + hi * 8]);
      bf16x8 kf1 = *reinterpret_cast<const bf16x8*>(&Ks[32 + q][c * 16 + hi * 8]);
      st0 = MFMA32(kf0, qf[c], st0);
      st1 = MFMA32(kf1, qf[c], st1);
    }

    // tile max (tree) + cross-hi
    float mx[16];
#pragma unroll
    for (int r = 0; r < 16; ++r) mx[r] = fmaxf(st0[r], st1[r]);
#pragma unroll
    for (int r = 0; r < 8; ++r) mx[r] = fmaxf(mx[r], mx[r + 8]);
#pragma unroll
    for (int r = 0; r < 4; ++r) mx[r] = fmaxf(mx[r], mx[r + 4]);
    float tm = fmaxf(fmaxf(mx[0], mx[1]), fmaxf(mx[2], mx[3]));
    tm = fmaxf(tm, __shfl_xor(tm, 32));

    // defer-max rescale
    float mcur = mrun;
    if (!__all(tm <= mcur + 8.0f)) {
      float mnew = fmaxf(mcur, tm);
      float al = __builtin_amdgcn_exp2f(mcur - mnew);
      mrun = mnew;
      mcur = mnew;
      lrun *= al;
#pragma unroll
      for (int r = 0; r < 16; ++r) {
        float ar = __shfl(al, (r & 3) + 8 * (r >> 2) + 4 * hi);
#pragma unroll
        for (int dc = 0; dc < 4; ++dc) o[dc][r] *= ar;
      }
    }

    // exp2 + pack pairs + partial sums (p never lives as 32 regs)
    unsigned pk[16];
    float s[16];
#pragma unroll
    for (int j = 0; j < 8; ++j) {
      float pa_ = __builtin_amdgcn_exp2f(st0[2 * j] - mcur);
      float pb_ = __builtin_amdgcn_exp2f(st0[2 * j + 1] - mcur);
      s[j] = pa_ + pb_;
      pk[j] = pack2(pa_, pb_);
    }
#pragma unroll
    for (int j = 0; j < 8; ++j) {
      float pa_ = __builtin_amdgcn_exp2f(st1[2 * j] - mcur);
      float pb_ = __builtin_amdgcn_exp2f(st1[2 * j + 1] - mcur);
      s[8 + j] = pa_ + pb_;
      pk[8 + j] = pack2(pa_, pb_);
    }
#pragma unroll
    for (int j = 0; j < 8; ++j) s[j] += s[j + 8];
#pragma unroll
    for (int j = 0; j < 4; ++j) s[j] += s[j + 4];
    lrun += (s[0] + s[1]) + (s[2] + s[3]);

    // assemble PV A-fragments via cross-half swaps
    union { unsigned u[4]; bf16x8 v; } pa0, pa1, pa2, pa3;
    swap32(pk[0],  pk[2],  hi, pa0.u[0], pa0.u[2]);
    swap32(pk[1],  pk[3],  hi, pa0.u[1], pa0.u[3]);
    swap32(pk[4],  pk[6],  hi, pa1.u[0], pa1.u[2]);
    swap32(pk[5],  pk[7],  hi, pa1.u[1], pa1.u[3]);
    swap32(pk[8],  pk[10], hi, pa2.u[0], pa2.u[2]);
    swap32(pk[9],  pk[11], hi, pa2.u[1], pa2.u[3]);
    swap32(pk[12], pk[14], hi, pa3.u[0], pa3.u[2]);
    swap32(pk[13], pk[15], hi, pa3.u[1], pa3.u[3]);

    // PV: O[q][d] += P[q][kv] V[kv][d], 4 kv-subtiles x 4 d-chunks
#pragma unroll
    for (int dc = 0; dc < 4; ++dc) {
      bf16x8 vf0 = *reinterpret_cast<const bf16x8*>(&Vs[dc * 32 + q][hi * 8]);
      bf16x8 vf1 = *reinterpret_cast<const bf16x8*>(&Vs[dc * 32 + q][16 + hi * 8]);
      bf16x8 vf2 = *reinterpret_cast<const bf16x8*>(&Vs[dc * 32 + q][32 + hi * 8]);
      bf16x8 vf3 = *reinterpret_cast<const bf16x8*>(&Vs[dc * 32 + q][48 + hi * 8]);
      o[dc] = MFMA32(pa0.v, vf0, o[dc]);
      o[dc] = MFMA32(pa1.v, vf1, o[dc]);
      o[dc] = MFMA32(pa2.v, vf2, o[dc]);
      o[dc] = MFMA32(pa3.v, vf3, o[dc]);
    }
  }

  // epilogue: combine per-lane partial sums, normalize, store
  float ltot = lrun + __shfl_xor(lrun, 32);
  float inv = 1.f / ltot;     // valid for q = lane&31
#pragma unroll
  for (int r = 0; r < 16; ++r) {
    const int qr = (r & 3) + 8 * (r >> 2) + 4 * hi;
    float invr = __shfl(inv, qr);
    long row = (long)b * 2048 + q0 + qr;
#pragma unroll
    for (int dc = 0; dc < 4; ++dc)
      Fg[row * 128 + dc * 32 + q] = f2bf(o[dc][r] * invr);
  }
}

extern "C" void kernel_launch(void* const* d_in, const int* in_sizes, int n_in,
                              void* d_out, int out_size, void* d_ws, size_t ws_size,
                              hipStream_t stream)
{
  (void)in_sizes; (void)n_in; (void)out_size; (void)ws_size;
  const float* smiles = (const float*)d_in[0];
  const float* image  = (const float*)d_in[1];
  const float* Wv = (const float*)d_in[2]; const float* bv = (const float*)d_in[3];
  const float* Wk = (const float*)d_in[4]; const float* bk = (const float*)d_in[5];
  const float* Wq = (const float*)d_in[6]; const float* bq = (const float*)d_in[7];
  const float* Wd = (const float*)d_in[8]; const float* bd = (const float*)d_in[9];

  unsigned short* Qw = (unsigned short*)d_ws;          // [32][2048][128] bf16
  unsigned short* Kw = Qw + 8388608;                   // [32][2048][128] bf16
  unsigned short* Vw = Kw + 8388608;                   // [32][128][2048] bf16 (V^T)
  unsigned short* Fw = Vw + 8388608;                   // [32][2048][128] bf16 fusion

  // fold 1/sqrt(128) and log2(e) into Q so softmax uses exp2
  const float qscale = 1.4426950408889634f * 0.08838834764831845f;

  dim3 blk(256);
  proj_kernel<true, 0><<<dim3(1024), blk, 0, stream>>>(image,  Wq, bq, Qw, qscale);
  proj_kernel<true, 0><<<dim3(1024), blk, 0, stream>>>(smiles, Wk, bk, Kw, 1.f);
  proj_kernel<true, 1><<<dim3(1024), blk, 0, stream>>>(smiles, Wv, bv, Vw, 1.f);
  attn_kernel<<<dim3(16, 32), blk, 0, stream>>>(Qw, Kw, Vw, Fw);
  proj_kernel<false, 2><<<dim3(1024), blk, 0, stream>>>(Fw, Wd, bd, (float*)d_out, 1.f);
}

// Round 12
// 132.579 us; speedup vs baseline: 1.2273x; 1.2273x over previous
//
#include <hip/hip_runtime.h>
#include <hip/hip_bf16.h>

typedef __attribute__((ext_vector_type(4))) float f32x4;
typedef __attribute__((ext_vector_type(16))) float f32x16;
typedef __attribute__((ext_vector_type(8))) short bf16x8;
typedef __attribute__((ext_vector_type(4))) unsigned int uint4v;
typedef __attribute__((ext_vector_type(2))) unsigned int uint2v;

#define MFMA16(a, b, c) __builtin_amdgcn_mfma_f32_16x16x32_bf16(a, b, c, 0, 0, 0)
#define MFMA32(a, b, c) __builtin_amdgcn_mfma_f32_32x32x16_bf16(a, b, c, 0, 0, 0)

__device__ __forceinline__ unsigned short f2bf(float f) {
  union { float f; unsigned u; } v; v.f = f;
  unsigned r = v.u + 0x7fffu + ((v.u >> 16) & 1u);
  return (unsigned short)(r >> 16);
}
// native converts (compiler pairs these into v_cvt_pk_bf16_f32 — m240)
__device__ __forceinline__ unsigned pack2(float a, float b) {
  union { __hip_bfloat162 h2; unsigned u; } cv;
  cv.h2 = __hip_bfloat162(__float2bfloat16(a), __float2bfloat16(b));
  return cv.u;
}

// cross-half exchange (validated R10/R11): ox = hi? partner's b : own a;
// oy = hi? own b : partner's a.
__device__ __forceinline__ void swap32(unsigned a, unsigned b, int hi,
                                       unsigned& ox, unsigned& oy) {
#if __has_builtin(__builtin_amdgcn_permlane32_swap)
  uint2v r = __builtin_amdgcn_permlane32_swap(a, b, false, false);
  ox = r[0]; oy = r[1];
#else
  unsigned sb = __shfl_xor(b, 32);
  unsigned sa = __shfl_xor(a, 32);
  ox = hi ? sb : a;
  oy = hi ? b : sa;
#endif
}

// y = x @ W^T + b, optional scale, M=65536 rows, N=K=128.
template<bool IN_F32, int OUT_MODE>
__global__ __launch_bounds__(256)
void proj_kernel(const void* __restrict__ xin, const float* __restrict__ W,
                 const float* __restrict__ bias, void* __restrict__ yout,
                 float scale)
{
  __shared__ __align__(16) unsigned short Ws[128][136];
  __shared__ __align__(16) unsigned short Xs[64][136];
  const int t = threadIdx.x;
  const int wid = t >> 6;
  const int lane = t & 63;
  const int ln = lane & 15, g = lane >> 4;
  const long row0 = (long)blockIdx.x * 64;

  float bz[8];
#pragma unroll
  for (int tt = 0; tt < 8; ++tt) bz[tt] = bias[tt * 16 + ln];

#pragma unroll
  for (int i = 0; i < 16; ++i) {
    int idx = (i * 256 + t) * 4;
    int r = idx >> 7, c = idx & 127;
    const float4 w4 = *reinterpret_cast<const float4*>(W + idx);
    ushort4 wb;
    wb.x = f2bf(w4.x); wb.y = f2bf(w4.y); wb.z = f2bf(w4.z); wb.w = f2bf(w4.w);
    *reinterpret_cast<ushort4*>(&Ws[r][c]) = wb;
  }
  if (IN_F32) {
    const float* x = (const float*)xin;
#pragma unroll
    for (int i = 0; i < 8; ++i) {
      int idx = (i * 256 + t) * 4;
      int r = idx >> 7, c = idx & 127;
      const float4 x4 = *reinterpret_cast<const float4*>(x + row0 * 128 + idx);
      ushort4 xb;
      xb.x = f2bf(x4.x); xb.y = f2bf(x4.y); xb.z = f2bf(x4.z); xb.w = f2bf(x4.w);
      *reinterpret_cast<ushort4*>(&Xs[r][c]) = xb;
    }
  } else {
    const unsigned short* x = (const unsigned short*)xin;
#pragma unroll
    for (int i = 0; i < 4; ++i) {
      int idx = (i * 256 + t) * 8;
      int r = idx >> 7, c = idx & 127;
      *reinterpret_cast<uint4v*>(&Xs[r][c]) =
          *reinterpret_cast<const uint4v*>(x + row0 * 128 + idx);
    }
  }
  __syncthreads();

  f32x4 acc[8];
#pragma unroll
  for (int tt = 0; tt < 8; ++tt) acc[tt] = (f32x4){0.f, 0.f, 0.f, 0.f};

#pragma unroll
  for (int c = 0; c < 4; ++c) {
    bf16x8 af = *reinterpret_cast<const bf16x8*>(&Xs[wid * 16 + ln][c * 32 + g * 8]);
#pragma unroll
    for (int tt = 0; tt < 8; ++tt) {
      bf16x8 bfr = *reinterpret_cast<const bf16x8*>(&Ws[tt * 16 + ln][c * 32 + g * 8]);
      acc[tt] = MFMA16(af, bfr, acc[tt]);
    }
  }

#pragma unroll
  for (int tt = 0; tt < 8; ++tt) {
#pragma unroll
    for (int r = 0; r < 4; ++r) {
      long row = row0 + wid * 16 + g * 4 + r;
      int col = tt * 16 + ln;
      float val = (acc[tt][r] + bz[tt]) * scale;
      if (OUT_MODE == 2) {
        ((float*)yout)[row * 128 + col] = val;
      } else if (OUT_MODE == 0) {
        ((unsigned short*)yout)[row * 128 + col] = f2bf(val);
      } else {
        long bb = row >> 11, rr = row & 2047;
        ((unsigned short*)yout)[(bb * 128 + col) * 2048 + rr] = f2bf(val);
      }
    }
  }
}

// Flash attention, 32x32x16 MFMA, KVBLK=32 (R10 structure, best measured).
// 4 waves x 32 q-rows. Swapped QK^T; in-reg P via permlane swap; native cvt_pk
// packing; defer-max THR=8; T14 single-buffer staging (R8-proven skeleton);
// T5 setprio around MFMA clusters.
__global__ __launch_bounds__(256)
void attn_kernel(const unsigned short* __restrict__ Qg,
                 const unsigned short* __restrict__ Kg,
                 const unsigned short* __restrict__ Vtg,
                 unsigned short* __restrict__ Fg)
{
  __shared__ __align__(16) unsigned short Ks[32][136];
  __shared__ __align__(16) unsigned short Vs[128][40];

  const int t = threadIdx.x;          // 0..255
  const int lane = t & 63;
  const int q = lane & 31;
  const int hi = lane >> 5;
  const int wid = t >> 6;
  const int b = blockIdx.y;
  const int q0 = blockIdx.x * 128 + wid * 32;

  const unsigned short* Qb = Qg + (long)b * 2048 * 128;
  const unsigned short* Kb = Kg + (long)b * 2048 * 128;
  const unsigned short* Vb = Vtg + (long)b * 128 * 2048;

  // staging coords (2 b128 per thread each for K and V)
  const int kr = t >> 4, kc = (t & 15) * 8;   // K tile [32][128]: rows kr, kr+16
  const int vc = t >> 2, ko = (t & 3) * 8;    // V^T tile [128][32]: rows vc, vc+64

  // Q fragments (B-operand): qf[c][i] = Q[q0+q][c*16 + hi*8 + i]
  bf16x8 qf[8];
#pragma unroll
  for (int c = 0; c < 8; ++c)
    qf[c] = *reinterpret_cast<const bf16x8*>(
        Qb + (long)(q0 + q) * 128 + c * 16 + hi * 8);

  f32x16 o[4];
#pragma unroll
  for (int dc = 0; dc < 4; ++dc)
#pragma unroll
    for (int r = 0; r < 16; ++r) o[dc][r] = 0.f;
  float mrun = -1e30f;
  float lrun = 0.f;   // per-lane partial (own 16 kv of each tile)

  // prologue: issue tile 0's loads
  uint4v kreg0 = *reinterpret_cast<const uint4v*>(Kb + (long)kr * 128 + kc);
  uint4v kreg1 = *reinterpret_cast<const uint4v*>(Kb + (long)(kr + 16) * 128 + kc);
  uint4v vreg0 = *reinterpret_cast<const uint4v*>(Vb + (long)vc * 2048 + ko);
  uint4v vreg1 = *reinterpret_cast<const uint4v*>(Vb + (long)(vc + 64) * 2048 + ko);

  for (int kt = 0; kt < 64; ++kt) {
    __syncthreads();   // all waves done reading LDS from iteration kt-1
    *reinterpret_cast<uint4v*>(&Ks[kr][kc]) = kreg0;
    *reinterpret_cast<uint4v*>(&Ks[kr + 16][kc]) = kreg1;
    *reinterpret_cast<uint4v*>(&Vs[vc][ko]) = vreg0;
    *reinterpret_cast<uint4v*>(&Vs[vc + 64][ko]) = vreg1;
    __syncthreads();   // tile kt visible

    if (kt < 63) {     // T14: issue tile kt+1's loads now, consume next iter
      const int nv0 = (kt + 1) * 32;
      kreg0 = *reinterpret_cast<const uint4v*>(Kb + (long)(nv0 + kr) * 128 + kc);
      kreg1 = *reinterpret_cast<const uint4v*>(Kb + (long)(nv0 + kr + 16) * 128 + kc);
      vreg0 = *reinterpret_cast<const uint4v*>(Vb + (long)vc * 2048 + nv0 + ko);
      vreg1 = *reinterpret_cast<const uint4v*>(Vb + (long)(vc + 64) * 2048 + nv0 + ko);
    }

    // QK^T: S^T[kv][q], st reg r holds S^T[(r&3)+8*(r>>2)+4*hi][q]
    f32x16 st;
#pragma unroll
    for (int r = 0; r < 16; ++r) st[r] = 0.f;
    __builtin_amdgcn_s_setprio(1);
#pragma unroll
    for (int c = 0; c < 8; ++c) {
      bf16x8 kf = *reinterpret_cast<const bf16x8*>(&Ks[q][c * 16 + hi * 8]);
      st = MFMA32(kf, qf[c], st);
    }
    __builtin_amdgcn_s_setprio(0);

    // row max: 15 in-lane + 1 cross-hi
    float tm = st[0];
#pragma unroll
    for (int r = 1; r < 16; ++r) tm = fmaxf(tm, st[r]);
    tm = fmaxf(tm, __shfl_xor(tm, 32));

    // defer-max rescale
    float mcur = mrun;
    if (!__all(tm <= mcur + 8.0f)) {
      float mnew = fmaxf(mcur, tm);
      float al = __builtin_amdgcn_exp2f(mcur - mnew);
      mrun = mnew;
      mcur = mnew;
      lrun *= al;
#pragma unroll
      for (int r = 0; r < 16; ++r) {
        float ar = __shfl(al, (r & 3) + 8 * (r >> 2) + 4 * hi);
#pragma unroll
        for (int dc = 0; dc < 4; ++dc) o[dc][r] *= ar;
      }
    }

    // exp2 + pack pairs + partial sums
    unsigned pk[8];
    float s[8];
#pragma unroll
    for (int j = 0; j < 8; ++j) {
      float pa_ = __builtin_amdgcn_exp2f(st[2 * j] - mcur);
      float pb_ = __builtin_amdgcn_exp2f(st[2 * j + 1] - mcur);
      s[j] = pa_ + pb_;
      pk[j] = pack2(pa_, pb_);
    }
#pragma unroll
    for (int j = 0; j < 4; ++j) s[j] += s[j + 4];
    lrun += (s[0] + s[1]) + (s[2] + s[3]);

    // assemble PV A-fragments via cross-half swaps (validated mapping)
    union { unsigned u[4]; bf16x8 v; } pa0, pa1;
    swap32(pk[0], pk[2], hi, pa0.u[0], pa0.u[2]);
    swap32(pk[1], pk[3], hi, pa0.u[1], pa0.u[3]);
    swap32(pk[4], pk[6], hi, pa1.u[0], pa1.u[2]);
    swap32(pk[5], pk[7], hi, pa1.u[1], pa1.u[3]);

    // PV: O[q][d] += P[q][kv] V[kv][d]
    __builtin_amdgcn_s_setprio(1);
#pragma unroll
    for (int dc = 0; dc < 4; ++dc) {
      bf16x8 vf0 = *reinterpret_cast<const bf16x8*>(&Vs[dc * 32 + q][hi * 8]);
      bf16x8 vf1 = *reinterpret_cast<const bf16x8*>(&Vs[dc * 32 + q][16 + hi * 8]);
      o[dc] = MFMA32(pa0.v, vf0, o[dc]);
      o[dc] = MFMA32(pa1.v, vf1, o[dc]);
    }
    __builtin_amdgcn_s_setprio(0);
  }

  // epilogue: combine per-lane partial sums, normalize, store
  float ltot = lrun + __shfl_xor(lrun, 32);
  float inv = 1.f / ltot;     // valid for q = lane&31
#pragma unroll
  for (int r = 0; r < 16; ++r) {
    const int qr = (r & 3) + 8 * (r >> 2) + 4 * hi;
    float invr = __shfl(inv, qr);
    long row = (long)b * 2048 + q0 + qr;
#pragma unroll
    for (int dc = 0; dc < 4; ++dc)
      Fg[row * 128 + dc * 32 + q] = f2bf(o[dc][r] * invr);
  }
}

extern "C" void kernel_launch(void* const* d_in, const int* in_sizes, int n_in,
                              void* d_out, int out_size, void* d_ws, size_t ws_size,
                              hipStream_t stream)
{
  (void)in_sizes; (void)n_in; (void)out_size; (void)ws_size;
  const float* smiles = (const float*)d_in[0];
  const float* image  = (const float*)d_in[1];
  const float* Wv = (const float*)d_in[2]; const float* bv = (const float*)d_in[3];
  const float* Wk = (const float*)d_in[4]; const float* bk = (const float*)d_in[5];
  const float* Wq = (const float*)d_in[6]; const float* bq = (const float*)d_in[7];
  const float* Wd = (const float*)d_in[8]; const float* bd = (const float*)d_in[9];

  unsigned short* Qw = (unsigned short*)d_ws;          // [32][2048][128] bf16
  unsigned short* Kw = Qw + 8388608;                   // [32][2048][128] bf16
  unsigned short* Vw = Kw + 8388608;                   // [32][128][2048] bf16 (V^T)
  unsigned short* Fw = Vw + 8388608;                   // [32][2048][128] bf16 fusion

  // fold 1/sqrt(128) and log2(e) into Q so softmax uses exp2
  const float qscale = 1.4426950408889634f * 0.08838834764831845f;

  dim3 blk(256);
  proj_kernel<true, 0><<<dim3(1024), blk, 0, stream>>>(image,  Wq, bq, Qw, qscale);
  proj_kernel<true, 0><<<dim3(1024), blk, 0, stream>>>(smiles, Wk, bk, Kw, 1.f);
  proj_kernel<true, 1><<<dim3(1024), blk, 0, stream>>>(smiles, Wv, bv, Vw, 1.f);
  attn_kernel<<<dim3(16, 32), blk, 0, stream>>>(Qw, Kw, Vw, Fw);
  proj_kernel<false, 2><<<dim3(1024), blk, 0, stream>>>(Fw, Wd, bd, (float*)d_out, 1.f);
}

// Round 14
// 128.084 us; speedup vs baseline: 1.2704x; 1.0351x over previous
//
#include <hip/hip_runtime.h>
#include <hip/hip_bf16.h>

typedef __attribute__((ext_vector_type(4))) float f32x4;
typedef __attribute__((ext_vector_type(16))) float f32x16;
typedef __attribute__((ext_vector_type(8))) short bf16x8;
typedef __attribute__((ext_vector_type(4))) unsigned int uint4v;
typedef __attribute__((ext_vector_type(2))) unsigned int uint2v;

#define MFMA16(a, b, c) __builtin_amdgcn_mfma_f32_16x16x32_bf16(a, b, c, 0, 0, 0)
#define MFMA32(a, b, c) __builtin_amdgcn_mfma_f32_32x32x16_bf16(a, b, c, 0, 0, 0)

__device__ __forceinline__ unsigned short f2bf(float f) {
  union { float f; unsigned u; } v; v.f = f;
  unsigned r = v.u + 0x7fffu + ((v.u >> 16) & 1u);
  return (unsigned short)(r >> 16);
}
__device__ __forceinline__ unsigned pack2(float a, float b) {
  union { __hip_bfloat162 h2; unsigned u; } cv;
  cv.h2 = __hip_bfloat162(__float2bfloat16(a), __float2bfloat16(b));
  return cv.u;
}

// cross-half exchange (validated R10-R12)
__device__ __forceinline__ void swap32(unsigned a, unsigned b, int hi,
                                       unsigned& ox, unsigned& oy) {
#if __has_builtin(__builtin_amdgcn_permlane32_swap)
  uint2v r = __builtin_amdgcn_permlane32_swap(a, b, false, false);
  ox = r[0]; oy = r[1];
#else
  unsigned sb = __shfl_xor(b, 32);
  unsigned sa = __shfl_xor(a, 32);
  ox = hi ? sb : a;
  oy = hi ? b : sa;
#endif
}

// y = x @ W^T + b, M=65536 rows, N=K=128.
// OUT_MODE: 0 = bf16 [M][128]; 1 = bf16 transposed [B][128][2048]; 2 = f32 [M][128]
template<bool IN_F32, int OUT_MODE>
__global__ __launch_bounds__(256)
void proj_kernel(const void* __restrict__ xin, const float* __restrict__ W,
                 const float* __restrict__ bias, void* __restrict__ yout,
                 float scale)
{
  __shared__ __align__(16) unsigned short Ws[128][136];
  __shared__ __align__(16) unsigned short Xs[64][136];
  const int t = threadIdx.x;
  const int wid = t >> 6;
  const int lane = t & 63;
  const int ln = lane & 15, g = lane >> 4;
  const long row0 = (long)blockIdx.x * 64;

  float bz[8];
#pragma unroll
  for (int tt = 0; tt < 8; ++tt) bz[tt] = bias[tt * 16 + ln];

#pragma unroll
  for (int i = 0; i < 16; ++i) {
    int idx = (i * 256 + t) * 4;
    int r = idx >> 7, c = idx & 127;
    const float4 w4 = *reinterpret_cast<const float4*>(W + idx);
    ushort4 wb;
    wb.x = f2bf(w4.x); wb.y = f2bf(w4.y); wb.z = f2bf(w4.z); wb.w = f2bf(w4.w);
    *reinterpret_cast<ushort4*>(&Ws[r][c]) = wb;
  }
  if (IN_F32) {
    const float* x = (const float*)xin;
#pragma unroll
    for (int i = 0; i < 8; ++i) {
      int idx = (i * 256 + t) * 4;
      int r = idx >> 7, c = idx & 127;
      const float4 x4 = *reinterpret_cast<const float4*>(x + row0 * 128 + idx);
      ushort4 xb;
      xb.x = f2bf(x4.x); xb.y = f2bf(x4.y); xb.z = f2bf(x4.z); xb.w = f2bf(x4.w);
      *reinterpret_cast<ushort4*>(&Xs[r][c]) = xb;
    }
  } else {
    const unsigned short* x = (const unsigned short*)xin;
#pragma unroll
    for (int i = 0; i < 4; ++i) {
      int idx = (i * 256 + t) * 8;
      int r = idx >> 7, c = idx & 127;
      *reinterpret_cast<uint4v*>(&Xs[r][c]) =
          *reinterpret_cast<const uint4v*>(x + row0 * 128 + idx);
    }
  }
  __syncthreads();

  f32x4 acc[8];
#pragma unroll
  for (int tt = 0; tt < 8; ++tt) acc[tt] = (f32x4){0.f, 0.f, 0.f, 0.f};

#pragma unroll
  for (int c = 0; c < 4; ++c) {
    bf16x8 af = *reinterpret_cast<const bf16x8*>(&Xs[wid * 16 + ln][c * 32 + g * 8]);
#pragma unroll
    for (int tt = 0; tt < 8; ++tt) {
      bf16x8 bfr = *reinterpret_cast<const bf16x8*>(&Ws[tt * 16 + ln][c * 32 + g * 8]);
      acc[tt] = MFMA16(af, bfr, acc[tt]);
    }
  }

#pragma unroll
  for (int tt = 0; tt < 8; ++tt) {
#pragma unroll
    for (int r = 0; r < 4; ++r) {
      long row = row0 + wid * 16 + g * 4 + r;
      int col = tt * 16 + ln;
      float val = (acc[tt][r] + bz[tt]) * scale;
      if (OUT_MODE == 2) {
        ((float*)yout)[row * 128 + col] = val;
      } else if (OUT_MODE == 0) {
        ((unsigned short*)yout)[row * 128 + col] = f2bf(val);
      } else {
        long bb = row >> 11, rr = row & 2047;
        ((unsigned short*)yout)[(bb * 128 + col) * 2048 + rr] = f2bf(val);
      }
    }
  }
}

// Fused K+V projection: stages X once, runs two weight phases (Wk -> K rows,
// then Wv -> V^T). Saves one full 32MB read of smiles + one launch.
__global__ __launch_bounds__(256)
void proj_kv_kernel(const float* __restrict__ x,
                    const float* __restrict__ Wk, const float* __restrict__ bk,
                    const float* __restrict__ Wv, const float* __restrict__ bv,
                    unsigned short* __restrict__ Kout,
                    unsigned short* __restrict__ Vout)
{
  __shared__ __align__(16) unsigned short Ws[128][136];
  __shared__ __align__(16) unsigned short Xs[64][136];
  const int t = threadIdx.x;
  const int wid = t >> 6;
  const int lane = t & 63;
  const int ln = lane & 15, g = lane >> 4;
  const long row0 = (long)blockIdx.x * 64;

  float bzk[8], bzv[8];
#pragma unroll
  for (int tt = 0; tt < 8; ++tt) { bzk[tt] = bk[tt * 16 + ln]; bzv[tt] = bv[tt * 16 + ln]; }

  // stage X tile (once) and Wk
#pragma unroll
  for (int i = 0; i < 8; ++i) {
    int idx = (i * 256 + t) * 4;
    int r = idx >> 7, c = idx & 127;
    const float4 x4 = *reinterpret_cast<const float4*>(x + row0 * 128 + idx);
    ushort4 xb;
    xb.x = f2bf(x4.x); xb.y = f2bf(x4.y); xb.z = f2bf(x4.z); xb.w = f2bf(x4.w);
    *reinterpret_cast<ushort4*>(&Xs[r][c]) = xb;
  }
#pragma unroll
  for (int i = 0; i < 16; ++i) {
    int idx = (i * 256 + t) * 4;
    int r = idx >> 7, c = idx & 127;
    const float4 w4 = *reinterpret_cast<const float4*>(Wk + idx);
    ushort4 wb;
    wb.x = f2bf(w4.x); wb.y = f2bf(w4.y); wb.z = f2bf(w4.z); wb.w = f2bf(w4.w);
    *reinterpret_cast<ushort4*>(&Ws[r][c]) = wb;
  }
  __syncthreads();

  f32x4 acc[8];
#pragma unroll
  for (int tt = 0; tt < 8; ++tt) acc[tt] = (f32x4){0.f, 0.f, 0.f, 0.f};
#pragma unroll
  for (int c = 0; c < 4; ++c) {
    bf16x8 af = *reinterpret_cast<const bf16x8*>(&Xs[wid * 16 + ln][c * 32 + g * 8]);
#pragma unroll
    for (int tt = 0; tt < 8; ++tt) {
      bf16x8 bfr = *reinterpret_cast<const bf16x8*>(&Ws[tt * 16 + ln][c * 32 + g * 8]);
      acc[tt] = MFMA16(af, bfr, acc[tt]);
    }
  }
#pragma unroll
  for (int tt = 0; tt < 8; ++tt)
#pragma unroll
    for (int r = 0; r < 4; ++r) {
      long row = row0 + wid * 16 + g * 4 + r;
      Kout[row * 128 + tt * 16 + ln] = f2bf(acc[tt][r] + bzk[tt]);
    }

  __syncthreads();   // all Ws reads done before restaging
#pragma unroll
  for (int i = 0; i < 16; ++i) {
    int idx = (i * 256 + t) * 4;
    int r = idx >> 7, c = idx & 127;
    const float4 w4 = *reinterpret_cast<const float4*>(Wv + idx);
    ushort4 wb;
    wb.x = f2bf(w4.x); wb.y = f2bf(w4.y); wb.z = f2bf(w4.z); wb.w = f2bf(w4.w);
    *reinterpret_cast<ushort4*>(&Ws[r][c]) = wb;
  }
  __syncthreads();

#pragma unroll
  for (int tt = 0; tt < 8; ++tt) acc[tt] = (f32x4){0.f, 0.f, 0.f, 0.f};
#pragma unroll
  for (int c = 0; c < 4; ++c) {
    bf16x8 af = *reinterpret_cast<const bf16x8*>(&Xs[wid * 16 + ln][c * 32 + g * 8]);
#pragma unroll
    for (int tt = 0; tt < 8; ++tt) {
      bf16x8 bfr = *reinterpret_cast<const bf16x8*>(&Ws[tt * 16 + ln][c * 32 + g * 8]);
      acc[tt] = MFMA16(af, bfr, acc[tt]);
    }
  }
#pragma unroll
  for (int tt = 0; tt < 8; ++tt)
#pragma unroll
    for (int r = 0; r < 4; ++r) {
      long row = row0 + wid * 16 + g * 4 + r;
      long bb = row >> 11, rr = row & 2047;
      Vout[(bb * 128 + tt * 16 + ln) * 2048 + rr] = f2bf(acc[tt][r] + bzv[tt]);
    }
}

// Flash attention (R12 body, unchanged) + XCD-aware 1-D grid swizzle:
// all 16 q-blocks of a batch land on the same XCD (bid%8 round-robin model).
__global__ __launch_bounds__(256)
void attn_kernel(const unsigned short* __restrict__ Qg,
                 const unsigned short* __restrict__ Kg,
                 const unsigned short* __restrict__ Vtg,
                 unsigned short* __restrict__ Fg)
{
  __shared__ __align__(16) unsigned short Ks[32][136];
  __shared__ __align__(16) unsigned short Vs[128][40];

  const int t = threadIdx.x;          // 0..255
  const int lane = t & 63;
  const int q = lane & 31;
  const int hi = lane >> 5;
  const int wid = t >> 6;

  // XCD swizzle: g = (b%8) + 8*((b/8)*16 + j)  (bijective over 512)
  const int gbid = blockIdx.x;
  const int k_ = gbid >> 3, r_ = gbid & 7;
  const int b = r_ + 8 * (k_ >> 4);
  const int j = k_ & 15;
  const int q0 = j * 128 + wid * 32;

  const unsigned short* Qb = Qg + (long)b * 2048 * 128;
  const unsigned short* Kb = Kg + (long)b * 2048 * 128;
  const unsigned short* Vb = Vtg + (long)b * 128 * 2048;

  const int kr = t >> 4, kc = (t & 15) * 8;   // K tile [32][128]: rows kr, kr+16
  const int vc = t >> 2, ko = (t & 3) * 8;    // V^T tile [128][32]: rows vc, vc+64

  bf16x8 qf[8];
#pragma unroll
  for (int c = 0; c < 8; ++c)
    qf[c] = *reinterpret_cast<const bf16x8*>(
        Qb + (long)(q0 + q) * 128 + c * 16 + hi * 8);

  f32x16 o[4];
#pragma unroll
  for (int dc = 0; dc < 4; ++dc)
#pragma unroll
    for (int r = 0; r < 16; ++r) o[dc][r] = 0.f;
  float mrun = -1e30f;
  float lrun = 0.f;

  uint4v kreg0 = *reinterpret_cast<const uint4v*>(Kb + (long)kr * 128 + kc);
  uint4v kreg1 = *reinterpret_cast<const uint4v*>(Kb + (long)(kr + 16) * 128 + kc);
  uint4v vreg0 = *reinterpret_cast<const uint4v*>(Vb + (long)vc * 2048 + ko);
  uint4v vreg1 = *reinterpret_cast<const uint4v*>(Vb + (long)(vc + 64) * 2048 + ko);

  for (int kt = 0; kt < 64; ++kt) {
    __syncthreads();
    *reinterpret_cast<uint4v*>(&Ks[kr][kc]) = kreg0;
    *reinterpret_cast<uint4v*>(&Ks[kr + 16][kc]) = kreg1;
    *reinterpret_cast<uint4v*>(&Vs[vc][ko]) = vreg0;
    *reinterpret_cast<uint4v*>(&Vs[vc + 64][ko]) = vreg1;
    __syncthreads();

    if (kt < 63) {     // T14: issue next tile's loads now
      const int nv0 = (kt + 1) * 32;
      kreg0 = *reinterpret_cast<const uint4v*>(Kb + (long)(nv0 + kr) * 128 + kc);
      kreg1 = *reinterpret_cast<const uint4v*>(Kb + (long)(nv0 + kr + 16) * 128 + kc);
      vreg0 = *reinterpret_cast<const uint4v*>(Vb + (long)vc * 2048 + nv0 + ko);
      vreg1 = *reinterpret_cast<const uint4v*>(Vb + (long)(vc + 64) * 2048 + nv0 + ko);
    }

    f32x16 st;
#pragma unroll
    for (int r = 0; r < 16; ++r) st[r] = 0.f;
    __builtin_amdgcn_s_setprio(1);
#pragma unroll
    for (int c = 0; c < 8; ++c) {
      bf16x8 kf = *reinterpret_cast<const bf16x8*>(&Ks[q][c * 16 + hi * 8]);
      st = MFMA32(kf, qf[c], st);
    }
    __builtin_amdgcn_s_setprio(0);

    float tm = st[0];
#pragma unroll
    for (int r = 1; r < 16; ++r) tm = fmaxf(tm, st[r]);
    tm = fmaxf(tm, __shfl_xor(tm, 32));

    float mcur = mrun;
    if (!__all(tm <= mcur + 8.0f)) {
      float mnew = fmaxf(mcur, tm);
      float al = __builtin_amdgcn_exp2f(mcur - mnew);
      mrun = mnew;
      mcur = mnew;
      lrun *= al;
#pragma unroll
      for (int r = 0; r < 16; ++r) {
        float ar = __shfl(al, (r & 3) + 8 * (r >> 2) + 4 * hi);
#pragma unroll
        for (int dc = 0; dc < 4; ++dc) o[dc][r] *= ar;
      }
    }

    unsigned pk[8];
    float s[8];
#pragma unroll
    for (int j2 = 0; j2 < 8; ++j2) {
      float pa_ = __builtin_amdgcn_exp2f(st[2 * j2] - mcur);
      float pb_ = __builtin_amdgcn_exp2f(st[2 * j2 + 1] - mcur);
      s[j2] = pa_ + pb_;
      pk[j2] = pack2(pa_, pb_);
    }
#pragma unroll
    for (int j2 = 0; j2 < 4; ++j2) s[j2] += s[j2 + 4];
    lrun += (s[0] + s[1]) + (s[2] + s[3]);

    union { unsigned u[4]; bf16x8 v; } pa0, pa1;
    swap32(pk[0], pk[2], hi, pa0.u[0], pa0.u[2]);
    swap32(pk[1], pk[3], hi, pa0.u[1], pa0.u[3]);
    swap32(pk[4], pk[6], hi, pa1.u[0], pa1.u[2]);
    swap32(pk[5], pk[7], hi, pa1.u[1], pa1.u[3]);

    __builtin_amdgcn_s_setprio(1);
#pragma unroll
    for (int dc = 0; dc < 4; ++dc) {
      bf16x8 vf0 = *reinterpret_cast<const bf16x8*>(&Vs[dc * 32 + q][hi * 8]);
      bf16x8 vf1 = *reinterpret_cast<const bf16x8*>(&Vs[dc * 32 + q][16 + hi * 8]);
      o[dc] = MFMA32(pa0.v, vf0, o[dc]);
      o[dc] = MFMA32(pa1.v, vf1, o[dc]);
    }
    __builtin_amdgcn_s_setprio(0);
  }

  float ltot = lrun + __shfl_xor(lrun, 32);
  float inv = 1.f / ltot;
#pragma unroll
  for (int r = 0; r < 16; ++r) {
    const int qr = (r & 3) + 8 * (r >> 2) + 4 * hi;
    float invr = __shfl(inv, qr);
    long row = (long)b * 2048 + q0 + qr;
#pragma unroll
    for (int dc = 0; dc < 4; ++dc)
      Fg[row * 128 + dc * 32 + q] = f2bf(o[dc][r] * invr);
  }
}

extern "C" void kernel_launch(void* const* d_in, const int* in_sizes, int n_in,
                              void* d_out, int out_size, void* d_ws, size_t ws_size,
                              hipStream_t stream)
{
  (void)in_sizes; (void)n_in; (void)out_size; (void)ws_size;
  const float* smiles = (const float*)d_in[0];
  const float* image  = (const float*)d_in[1];
  const float* Wv = (const float*)d_in[2]; const float* bv = (const float*)d_in[3];
  const float* Wk = (const float*)d_in[4]; const float* bk = (const float*)d_in[5];
  const float* Wq = (const float*)d_in[6]; const float* bq = (const float*)d_in[7];
  const float* Wd = (const float*)d_in[8]; const float* bd = (const float*)d_in[9];

  unsigned short* Qw = (unsigned short*)d_ws;          // [32][2048][128] bf16
  unsigned short* Kw = Qw + 8388608;                   // [32][2048][128] bf16
  unsigned short* Vw = Kw + 8388608;                   // [32][128][2048] bf16 (V^T)
  unsigned short* Fw = Vw + 8388608;                   // [32][2048][128] bf16 fusion

  const float qscale = 1.4426950408889634f * 0.08838834764831845f;

  dim3 blk(256);
  proj_kernel<true, 0><<<dim3(1024), blk, 0, stream>>>(image, Wq, bq, Qw, qscale);
  proj_kv_kernel<<<dim3(1024), blk, 0, stream>>>(smiles, Wk, bk, Wv, bv, Kw, Vw);
  attn_kernel<<<dim3(512), blk, 0, stream>>>(Qw, Kw, Vw, Fw);
  proj_kernel<false, 2><<<dim3(1024), blk, 0, stream>>>(Fw, Wd, bd, (float*)d_out, 1.f);
}